// Round 6
// baseline (116.487 us; speedup 1.0000x reference)
//
#include <hip/hip_runtime.h>
#include <hip/hip_bf16.h>

#define CC 64
#define HH 128
#define WW 128
#define OO 576   // C * K * K
#define HW (HH * WW)

typedef __attribute__((ext_vector_type(8))) short short8;
typedef __attribute__((ext_vector_type(4))) float floatx4;

__device__ __forceinline__ unsigned short f2bf(float f) {
    unsigned u = __float_as_uint(f);
    u = (u + 0x7FFFu + ((u >> 16) & 1u)) >> 16;   // RTNE
    return (unsigned short)u;
}

// Pre-convert W_gen (576x64 fp32) -> bf16 in workspace
__global__ void ACDA_wconv_kernel(const float* __restrict__ Wg,
                                  unsigned short* __restrict__ Wb) {
    int i = blockIdx.x * 256 + threadIdx.x;
    if (i < OO * CC) Wb[i] = f2bf(Wg[i]);
}

// 256-thread block = 4 waves; wave wv owns 16 output channels x 64 pixels.
//
// R5 post-mortem: still ~46us; VGPR=76 proves the register patch
// double-buffer was dissolved by the allocator -> serial ~224cyc/load chain
// (38k-cyc wave lifetime / ~170 loads). This round: patch pipeline moved to
// LDS via __builtin_amdgcn_global_load_lds (fire-and-forget, ZERO register
// cost, compiler cannot sink it). Double-buffered PLDS per wave; one
// explicit vmcnt(0) per chunk, covered by >=600cyc of MFMA+combine.
__global__ __launch_bounds__(256, 4) void ACDA_main_kernel(
    const float* __restrict__ x, const unsigned short* __restrict__ Wb,
    const float* __restrict__ bg, float* __restrict__ out)
{
    // Union: Bl (64px x 72ch bf16 = 9216B) aliases FbufT (dead until after
    // fragment reads, barrier-protected). FbufT stride 20 floats: bank
    // starts {0,20,8,28,16,4,24,12} -> conflict-free b128 (measured 0).
    __shared__ __align__(16) char smem[20480];
    float (*FbufT)[64][20] = reinterpret_cast<float(*)[64][20]>(smem);          // [4][64][20]
    unsigned short (*Bl)[72] = reinterpret_cast<unsigned short(*)[72]>(smem);   // [64][72]
    // Patch staging: [wave][dbuf][row][lane]. global_load_lds writes
    // base+lane*4 (linear, conflict-free); consume reads [r][lane] ->
    // bank = lane%32, conflict-free. 32768B; total LDS 53248 < 64KB.
    __shared__ float PLDS[4][2][16][64];

    const int tid  = threadIdx.x;
    const int lane = tid & 63;
    const int wv   = tid >> 6;       // 16-channel group (wave-uniform)
    const int quad = lane >> 4;
    const int l16  = lane & 15;

    // Bijective XCD swizzle: 2048 blocks, 8 XCDs, 256 contiguous work items
    // per XCD => each XCD streams one batch image (proven: FETCH 85->17 MB).
    const int bid = blockIdx.x;
    const int wk  = (bid & 7) * 256 + (bid >> 3);
    const int seg = wk & 1;
    const int h   = (wk >> 1) & 127;
    const int b   = wk >> 8;
    const int w0  = seg << 6;

    const float* xb = x + (size_t)b * CC * HW;

    // ---- combine-phase per-lane precompute (clamped cols/rows + kill masks) ----
    int wA = w0 + lane - 1; bool badA = (wA < 0);   if (badA) wA = 0;
    int wB = w0 + lane;
    int wC = w0 + lane + 1; bool badC = (wC > 127); if (badC) wC = 127;
    int rt[3]; bool rbad[3];
#pragma unroll
    for (int di = 0; di < 3; ++di) {
        int rr = h + di - 1;
        rbad[di] = (rr < 0) || (rr > 127);
        rr = rr < 0 ? 0 : (rr > 127 ? 127 : rr);
        rt[di] = rr * WW;
    }
    const int wsel[3]  = {wA, wB, wC};
    const bool wbad[3] = {badA, false, badC};
    const int soffC = wv * 16 * HW;
    int  pb[3][3]; bool bad[3][3];
#pragma unroll
    for (int di = 0; di < 3; ++di)
#pragma unroll
        for (int dj = 0; dj < 3; ++dj) {
            pb[di][dj]  = soffC + rt[di] + wsel[dj];
            bad[di][dj] = rbad[di] || wbad[dj];
        }

    // Stage chunk T's 16 patch rows into PLDS[wv][BUF]: one global_load_lds
    // per (c,di,dj) row; per-lane GLOBAL addr (clamped, always valid),
    // wave-uniform LDS base; HW scatters lane i -> base + 4*i.
#define STAGEP(T, BUF) do {                                                   \
        _Pragma("unroll")                                                     \
        for (int r_ = 0; r_ < 16; ++r_) {                                     \
            const int idx_ = (T) * 16 + r_;                                   \
            const int c_   = idx_ / 9;                                        \
            const int kk_  = idx_ - 9 * c_;                                   \
            const int di_  = kk_ / 3;                                         \
            const int dj_  = kk_ - 3 * di_;                                   \
            const float* g_ = xb + pb[di_][dj_] + c_ * HW;                    \
            __builtin_amdgcn_global_load_lds(                                 \
                (const __attribute__((address_space(1))) unsigned int*)g_,    \
                (__attribute__((address_space(3))) unsigned int*)&PLDS[wv][BUF][r_][0], \
                4, 0, 0);                                                     \
        }                                                                     \
    } while (0)

#define LOADA(T, A0, A1, BV) do {                                         \
        const int obase_ = wv * 144 + (T) * 16;                           \
        const unsigned short* wrow_ = Wb + (obase_ + l16) * CC + quad * 8;\
        (A0) = *(const short8*)(wrow_);                                   \
        (A1) = *(const short8*)(wrow_ + 32);                              \
        (BV) = *(const floatx4*)(bg + obase_ + quad * 4);                 \
    } while (0)

    // Fire chunk-0 patch stage FIRST: lands under B-staging + 2 barriers.
    STAGEP(0, 0);

    // ---- cooperative B-tile staging: wave wv packs channels [wv*16,+16) ----
    {
        const int w = w0 + lane;
#pragma unroll
        for (int cc = 0; cc < 16; cc += 2) {
            const int c = wv * 16 + cc;
            float f0 = xb[(c * HH + h) * WW + w];
            float f1 = xb[((c + 1) * HH + h) * WW + w];
            __hip_bfloat162 p = __float22bfloat162_rn(make_float2(f0, f1));
            unsigned u;
            __builtin_memcpy(&u, &p, 4);
            *(unsigned*)&Bl[lane][c] = u;
        }
    }

    float oacc[16];
#pragma unroll
    for (int i = 0; i < 16; ++i) oacc[i] = 0.f;

    short8 a0A, a1A, a0B, a1B;
    floatx4 bvA, bvB;
    LOADA(0, a0A, a1A, bvA);

    __syncthreads();   // Bl fully written

    // ---- B fragments from LDS (shared across the 4 waves) ----
    short8 bfrag[4][2];
#pragma unroll
    for (int nt = 0; nt < 4; ++nt)
#pragma unroll
        for (int ks = 0; ks < 2; ++ks)
            bfrag[nt][ks] = *(const short8*)&Bl[nt * 16 + l16][ks * 32 + quad * 8];

    __syncthreads();   // all waves done reading Bl; FbufT may overwrite it

    // One chunk: MFMA (bias as acc-init) -> Fbuf b128 store -> LOADA(t+1)
    // -> vmcnt(0) [stage(t) landed; >=600cyc of cover] -> combine from
    // Fbuf + PLDS[t&1] -> fire STAGEP(t+1) into the other buffer.
#define CHUNK(T, A0C, A1C, BVC, A0N, A1N, BVN) do {                       \
        _Pragma("unroll")                                                 \
        for (int nt_ = 0; nt_ < 4; ++nt_) {                               \
            floatx4 z_ = (BVC);   /* bias pre-ReLU as accumulator init */ \
            z_ = __builtin_amdgcn_mfma_f32_16x16x32_bf16((A0C), bfrag[nt_][0], z_, 0, 0, 0); \
            z_ = __builtin_amdgcn_mfma_f32_16x16x32_bf16((A1C), bfrag[nt_][1], z_, 0, 0, 0); \
            *(floatx4*)&FbufT[wv][nt_ * 16 + l16][quad * 4] = z_;         \
        }                                                                 \
        if ((T) < 8) LOADA((T) + 1, A0N, A1N, BVN);                       \
        asm volatile("s_waitcnt vmcnt(0)" ::: "memory");                  \
        _Pragma("unroll")                                                 \
        for (int g_ = 0; g_ < 4; ++g_) {                                  \
            floatx4 f4_ = *(const floatx4*)&FbufT[wv][lane][g_ * 4];      \
            _Pragma("unroll")                                             \
            for (int rr_ = 0; rr_ < 4; ++rr_) {                           \
                const int r_   = g_ * 4 + rr_;                            \
                const int idx_ = (T) * 16 + r_;                           \
                const int c_   = idx_ / 9;                                \
                const int kk_  = idx_ - 9 * c_;                           \
                const int di_  = kk_ / 3;                                 \
                const int dj_  = kk_ - 3 * di_;                           \
                float fv_ = fmaxf(f4_[rr_], 0.f);                         \
                float pv_ = PLDS[wv][(T) & 1][r_][lane];                  \
                if (bad[di_][dj_]) pv_ = 0.f;                             \
                oacc[c_] = fmaf(fv_, pv_, oacc[c_]);                      \
            }                                                             \
        }                                                                 \
        if ((T) < 8) STAGEP((T) + 1, ((T) + 1) & 1);                      \
    } while (0)

    CHUNK(0, a0A, a1A, bvA, a0B, a1B, bvB);
    CHUNK(1, a0B, a1B, bvB, a0A, a1A, bvA);
    CHUNK(2, a0A, a1A, bvA, a0B, a1B, bvB);
    CHUNK(3, a0B, a1B, bvB, a0A, a1A, bvA);
    CHUNK(4, a0A, a1A, bvA, a0B, a1B, bvB);
    CHUNK(5, a0B, a1B, bvB, a0A, a1A, bvA);
    CHUNK(6, a0A, a1A, bvA, a0B, a1B, bvB);
    CHUNK(7, a0B, a1B, bvB, a0A, a1A, bvA);
    CHUNK(8, a0A, a1A, bvA, a0B, a1B, bvB);

#undef CHUNK
#undef LOADA
#undef STAGEP

    float* ob = out + (size_t)b * CC * HW + h * WW + w0 + lane;
#pragma unroll
    for (int i = 0; i < 16; ++i)
        ob[(wv * 16 + i) * HW] = oacc[i];
}

extern "C" void kernel_launch(void* const* d_in, const int* in_sizes, int n_in,
                              void* d_out, int out_size, void* d_ws, size_t ws_size,
                              hipStream_t stream) {
    const float* x  = (const float*)d_in[0];
    const float* Wg = (const float*)d_in[1];
    const float* bg = (const float*)d_in[2];
    float* out = (float*)d_out;
    unsigned short* Wb = (unsigned short*)d_ws;   // 576*64*2 = 73728 B

    ACDA_wconv_kernel<<<dim3((OO * CC + 255) / 256), dim3(256), 0, stream>>>(Wg, Wb);
    ACDA_main_kernel<<<dim3(8 * 128 * 2), dim3(256), 0, stream>>>(x, Wb, bg, out);
}

// Round 7
// 113.561 us; speedup vs baseline: 1.0258x; 1.0258x over previous
//
#include <hip/hip_runtime.h>
#include <hip/hip_bf16.h>

#define CC 64
#define HH 128
#define WW 128
#define OO 576   // C * K * K
#define HW (HH * WW)

typedef __attribute__((ext_vector_type(8))) short short8;
typedef __attribute__((ext_vector_type(4))) float floatx4;

__device__ __forceinline__ unsigned short f2bf(float f) {
    unsigned u = __float_as_uint(f);
    u = (u + 0x7FFFu + ((u >> 16) & 1u)) >> 16;   // RTNE
    return (unsigned short)u;
}

// Pre-convert W_gen (576x64 fp32) -> bf16, PERMUTED to tap-major row order:
// dest row o' = kk*64 + c   <- src row o = c*9 + kk.
// Tap-major rows make the main loop's chunk index == tap kk (wave-uniform),
// so the combine's register indices are compile-time inside a ROLLED loop.
__global__ void ACDA_wconv_kernel(const float* __restrict__ Wg,
                                  unsigned short* __restrict__ Wb) {
    int i = blockIdx.x * 256 + threadIdx.x;
    if (i < OO * CC) {
        int o2  = i >> 6;          // dest row
        int col = i & 63;
        int kk  = o2 >> 6;         // 0..8
        int c   = o2 & 63;
        Wb[i] = f2bf(Wg[(c * 9 + kk) * CC + col]);
    }
}

// 256-thread block = 4 waves; wave wv owns 16 output channels x 64 pixels.
//
// R6 post-mortem: 9-way-unrolled macro bodies = ~30KB of code ~ L1 I$ size;
// waves drift through 9 distinct code regions -> I$ thrash explains the
// schedule-invariant ~47us with ALL pipes idle. This round: tap-major row
// permute makes chunk==tap (wave-uniform di,dj), so the chunk loop ROLLS
// (x2 unroll for A/bias double-buffer) -> ~2KB code. Data path unchanged
// from R5 (B-share via LDS, bias-as-acc-init, XCD swizzle, FbufT b128).
__global__ __launch_bounds__(256, 4) void ACDA_main_kernel(
    const float* __restrict__ x, const unsigned short* __restrict__ Wb,
    const float* __restrict__ bg, float* __restrict__ out)
{
    // Union: Bl (64px x 72ch bf16 = 9216B) aliases FbufT (dead until after
    // fragment reads, barrier-protected). FbufT stride 20 floats: bank
    // starts {0,20,8,28,16,4,24,12} -> conflict-free b128 (measured 0).
    __shared__ __align__(16) char smem[20480];
    float (*FbufT)[64][20] = reinterpret_cast<float(*)[64][20]>(smem);          // [4][64][20]
    unsigned short (*Bl)[72] = reinterpret_cast<unsigned short(*)[72]>(smem);   // [64][72]

    const int tid  = threadIdx.x;
    const int lane = tid & 63;
    const int wv   = tid >> 6;       // 16-channel group (wave-uniform)
    const int quad = lane >> 4;
    const int l16  = lane & 15;
    const int c0   = wv * 16;        // first channel owned by this wave

    // Bijective XCD swizzle: 2048 blocks, 8 XCDs, 256 contiguous work items
    // per XCD => each XCD streams one batch image (proven: FETCH 85->17 MB).
    const int bid = blockIdx.x;
    const int wk  = (bid & 7) * 256 + (bid >> 3);
    const int seg = wk & 1;
    const int h   = (wk >> 1) & 127;
    const int b   = wk >> 8;
    const int w0  = seg << 6;

    const float* xb = x + (size_t)b * CC * HW;

    // ---- per-lane clamped cols + edge masks (taps select among these) ----
    int wA = w0 + lane - 1; bool badA = (wA < 0);   if (badA) wA = 0;
    int wB = w0 + lane;
    int wC = w0 + lane + 1; bool badC = (wC > 127); if (badC) wC = 127;
    const int soffC = c0 * HW;

    // ---- cooperative B-tile staging: wave wv packs channels [c0,c0+16) ----
    {
        const int w = w0 + lane;
#pragma unroll
        for (int cc = 0; cc < 16; cc += 2) {
            const int c = c0 + cc;
            float f0 = xb[(c * HH + h) * WW + w];
            float f1 = xb[((c + 1) * HH + h) * WW + w];
            __hip_bfloat162 p = __float22bfloat162_rn(make_float2(f0, f1));
            unsigned u;
            __builtin_memcpy(&u, &p, 4);
            *(unsigned*)&Bl[lane][c] = u;
        }
    }

    float oacc[16];
#pragma unroll
    for (int i = 0; i < 16; ++i) oacc[i] = 0.f;

    // A-fragments (tap-major rows) + bias gather for tap KK.
    // Row o' = KK*64 + c0 + l16 ; bias of C-row quad*4+reg = channel
    // c0+quad*4+reg at original index (channel*9 + KK).
    short8 a0A, a1A, a0B, a1B;
    floatx4 bvA, bvB;
#define LOADA(KK, A0, A1, BV) do {                                          \
        const unsigned short* wrow_ = Wb + ((KK) * 64 + c0 + l16) * CC + quad * 8; \
        (A0) = *(const short8*)(wrow_);                                     \
        (A1) = *(const short8*)(wrow_ + 32);                                \
        const float* bp_ = bg + (c0 + quad * 4) * 9 + (KK);                 \
        (BV)[0] = bp_[0]; (BV)[1] = bp_[9];                                 \
        (BV)[2] = bp_[18]; (BV)[3] = bp_[27];                               \
    } while (0)

    LOADA(0, a0A, a1A, bvA);

    __syncthreads();   // Bl fully written

    // ---- B fragments from LDS (shared across the 4 waves) ----
    short8 bfrag[4][2];
#pragma unroll
    for (int nt = 0; nt < 4; ++nt)
#pragma unroll
        for (int ks = 0; ks < 2; ++ks)
            bfrag[nt][ks] = *(const short8*)&Bl[nt * 16 + l16][ks * 32 + quad * 8];

    __syncthreads();   // all waves done reading Bl; FbufT may overwrite it

    // One tap: compute (di,dj) scalars -> issue 16 patch loads EARLY ->
    // MFMA (bias as acc-init) -> FbufT b128 roundtrip (covers patch latency)
    // -> combine. A/bias for the NEXT tap prefetched at body top.
#define BODY(KK, A0C, A1C, BVC, A0N, A1N, BVN, PREF) do {                   \
        if (PREF) LOADA((KK) + 1, A0N, A1N, BVN);                           \
        const int di_ = (KK) < 3 ? 0 : ((KK) < 6 ? 1 : 2);                  \
        const int dj_ = (KK) - 3 * di_;                                     \
        int rr_ = h + di_ - 1;                                              \
        const bool rbad_ = (rr_ < 0) || (rr_ > 127);                        \
        rr_ = rr_ < 0 ? 0 : (rr_ > 127 ? 127 : rr_);                        \
        const int  wsel_ = (dj_ == 0) ? wA : ((dj_ == 1) ? wB : wC);        \
        const bool wbad_ = (dj_ == 0) ? badA : ((dj_ == 2) ? badC : false); \
        const bool badk_ = rbad_ || wbad_;                                  \
        const int  pbk_  = soffC + rr_ * WW + wsel_;                        \
        float pv_[16];                                                      \
        _Pragma("unroll")                                                   \
        for (int r_ = 0; r_ < 16; ++r_) pv_[r_] = xb[pbk_ + r_ * HW];       \
        _Pragma("unroll")                                                   \
        for (int nt_ = 0; nt_ < 4; ++nt_) {                                 \
            floatx4 z_ = (BVC);   /* bias pre-ReLU as accumulator init */   \
            z_ = __builtin_amdgcn_mfma_f32_16x16x32_bf16((A0C), bfrag[nt_][0], z_, 0, 0, 0); \
            z_ = __builtin_amdgcn_mfma_f32_16x16x32_bf16((A1C), bfrag[nt_][1], z_, 0, 0, 0); \
            *(floatx4*)&FbufT[wv][nt_ * 16 + l16][quad * 4] = z_;           \
        }                                                                   \
        _Pragma("unroll")                                                   \
        for (int g_ = 0; g_ < 4; ++g_) {                                    \
            floatx4 f4_ = *(const floatx4*)&FbufT[wv][lane][g_ * 4];        \
            _Pragma("unroll")                                               \
            for (int rr2_ = 0; rr2_ < 4; ++rr2_) {                          \
                const int r_ = g_ * 4 + rr2_;                               \
                float fv_ = fmaxf(f4_[rr2_], 0.f);                          \
                float pvv_ = badk_ ? 0.f : pv_[r_];                         \
                oacc[r_] = fmaf(fv_, pvv_, oacc[r_]);                       \
            }                                                               \
        }                                                                   \
    } while (0)

    // Rolled x2 loop over taps 0..7, tail tap 8. Keep it ROLLED (code-size
    // is the whole point) — forbid unrolling.
#pragma unroll 1
    for (int kk = 0; kk < 8; kk += 2) {
        BODY(kk,     a0A, a1A, bvA, a0B, a1B, bvB, true);
        BODY(kk + 1, a0B, a1B, bvB, a0A, a1A, bvA, true);
    }
    BODY(8, a0A, a1A, bvA, a0B, a1B, bvB, false);

#undef BODY
#undef LOADA

    float* ob = out + (size_t)b * CC * HW + h * WW + w0 + lane;
#pragma unroll
    for (int i = 0; i < 16; ++i)
        ob[(c0 + i) * HW] = oacc[i];
}

extern "C" void kernel_launch(void* const* d_in, const int* in_sizes, int n_in,
                              void* d_out, int out_size, void* d_ws, size_t ws_size,
                              hipStream_t stream) {
    const float* x  = (const float*)d_in[0];
    const float* Wg = (const float*)d_in[1];
    const float* bg = (const float*)d_in[2];
    float* out = (float*)d_out;
    unsigned short* Wb = (unsigned short*)d_ws;   // 576*64*2 = 73728 B

    ACDA_wconv_kernel<<<dim3((OO * CC + 255) / 256), dim3(256), 0, stream>>>(Wg, Wb);
    ACDA_main_kernel<<<dim3(8 * 128 * 2), dim3(256), 0, stream>>>(x, Wb, bg, out);
}

// Round 8
// 113.437 us; speedup vs baseline: 1.0269x; 1.0011x over previous
//
#include <hip/hip_runtime.h>
#include <hip/hip_bf16.h>

#define CC 64
#define HH 128
#define WW 128
#define OO 576   // C * K * K
#define HW (HH * WW)

typedef __attribute__((ext_vector_type(8))) short short8;
typedef __attribute__((ext_vector_type(4))) float floatx4;

__device__ __forceinline__ unsigned short f2bf(float f) {
    unsigned u = __float_as_uint(f);
    u = (u + 0x7FFFu + ((u >> 16) & 1u)) >> 16;   // RTNE
    return (unsigned short)u;
}

// Pre-convert W_gen (576x64 fp32) -> bf16, PERMUTED to tap-major row order:
// dest row o' = kk*64 + c  <-  src row o = c*9 + kk. (R7-verified.)
__global__ void ACDA_wconv_kernel(const float* __restrict__ Wg,
                                  unsigned short* __restrict__ Wb) {
    int i = blockIdx.x * 256 + threadIdx.x;
    if (i < OO * CC) {
        int o2  = i >> 6;          // dest row
        int col = i & 63;
        int kk  = o2 >> 6;         // 0..8
        int c   = o2 & 63;
        Wb[i] = f2bf(Wg[(c * 9 + kk) * CC + col]);
    }
}

// R7 post-mortem: VGPR=56 proves the compiler again dissolved the register
// pipeline; combine's 16 patch loads serialize on ~200cy L2 latency -> 29k
// of the 38k-cycle wave lifetime. Fix: (1) whole x-slab for the block staged
// to LDS ONCE (cooperative, coalesced; x read once/block), patches+bfrag
// come from LDS (~120cy, dense issue); (2) combine kept in MFMA layout --
// lane owns (channel, pixel), patch read addressed directly -> FbufT
// transpose round-trip DELETED. One barrier total. LDS 52224B = 3 blocks/CU.
__global__ __launch_bounds__(256, 4) void ACDA_main_kernel(
    const float* __restrict__ x, const unsigned short* __restrict__ Wb,
    const float* __restrict__ bg, float* __restrict__ out)
{
    // S[di][c][s]: di = tap row (h-1,h,h+1 clamped), c = channel, s = col
    // slot (s=0 left halo=w0-1, s=1..64 -> w0..w0+63, s=65 right halo=w0+64).
    // Hot combine read: lanes (q,l16) -> bank (16q + l16 + const)%32 = exact
    // 2-way aliasing = free (m136). Stage writes: bank (4row+lane+1)%32,
    // lane-consecutive = conflict-free.
    __shared__ float S[3][64][68];   // 52224 B
    float* Sf = &S[0][0][0];

    const int tid  = threadIdx.x;
    const int lane = tid & 63;
    const int wv   = tid >> 6;       // 16-channel group (wave-uniform)
    const int quad = lane >> 4;
    const int l16  = lane & 15;
    const int c0   = wv * 16;

    // Bijective XCD swizzle (proven: FETCH 85->17 MB).
    const int bid = blockIdx.x;
    const int wk  = (bid & 7) * 256 + (bid >> 3);
    const int seg = wk & 1;
    const int h   = (wk >> 1) & 127;
    const int b   = wk >> 8;
    const int w0  = seg << 6;

    const float* xb = x + (size_t)b * CC * HW;

    // ---- cooperative slab staging: 192 rows x 64 bulk cols + 2 halo cols.
    // Wave w handles rows it*4+w: 64 consecutive cols per load = coalesced.
    {
        const int colT = tid & 63;
        const int row0 = tid >> 6;
#pragma unroll 8
        for (int it = 0; it < 48; ++it) {
            const int row = it * 4 + row0;          // = di*64 + c
            const int di  = row >> 6;
            const int c   = row & 63;
            int hh = h + di - 1; hh = hh < 0 ? 0 : (hh > 127 ? 127 : hh);
            Sf[row * 68 + colT + 1] = xb[c * HW + hh * WW + w0 + colT];
        }
        if (tid < 192) {                            // halos (one-time, tiny)
            const int di = tid >> 6;
            const int c  = tid & 63;
            int hh = h + di - 1; hh = hh < 0 ? 0 : (hh > 127 ? 127 : hh);
            const int base = c * HW + hh * WW;
            int colL = w0 - 1;  if (colL < 0)   colL = 0;
            int colR = w0 + 64; if (colR > 127) colR = 127;
            Sf[tid * 68]      = xb[base + colL];
            Sf[tid * 68 + 65] = xb[base + colR];
        }
    }
    __syncthreads();   // the ONLY barrier; S is read-only afterwards

    // ---- B fragments from slab row di=1 (x row h) ----
    // B[k][n]: n = l16 (pixel 16nt+l16), k = quad*8+j (channel), ks k-half.
    short8 bfrag[4][2];
#pragma unroll
    for (int nt = 0; nt < 4; ++nt)
#pragma unroll
        for (int ks = 0; ks < 2; ++ks) {
            short8 v;
#pragma unroll
            for (int j = 0; j < 8; j += 2) {
                const int c = ks * 32 + quad * 8 + j;
                float f0 = Sf[(64 + c) * 68 + nt * 16 + l16 + 1];
                float f1 = Sf[(64 + c + 1) * 68 + nt * 16 + l16 + 1];
                __hip_bfloat162 p = __float22bfloat162_rn(make_float2(f0, f1));
                unsigned u;
                __builtin_memcpy(&u, &p, 4);
                v[j]     = (short)(u & 0xffffu);
                v[j + 1] = (short)(u >> 16);
            }
            bfrag[nt][ks] = v;
        }

    // Output accumulator in MFMA layout: acc[nt][reg] <-> channel
    // c0+4*quad+reg, pixel w0+16*nt+l16. No transpose needed, ever.
    floatx4 acc[4];
#pragma unroll
    for (int nt = 0; nt < 4; ++nt) acc[nt] = floatx4{0.f, 0.f, 0.f, 0.f};

    // Edge kill masks (zero-padding): left only (dj=0, nt=0, l16=0, w0=0);
    // right only (dj=2, nt=3, l16=15, w0=64).
    const bool fc = (w0 + l16 == 0);
    const bool lc = (w0 + l16 == 79);

    short8 a0A, a1A, a0B, a1B;
    floatx4 bvA, bvB;
    // A rows o' = KK*64 + c0 + l16 (tap-major); bias of channel c0+4q+reg at
    // original index (channel*9 + KK).
#define LOADA(KK, A0, A1, BV) do {                                          \
        const unsigned short* wrow_ = Wb + ((KK) * 64 + c0 + l16) * CC + quad * 8; \
        (A0) = *(const short8*)(wrow_);                                     \
        (A1) = *(const short8*)(wrow_ + 32);                                \
        const float* bp_ = bg + (c0 + quad * 4) * 9 + (KK);                 \
        (BV)[0] = bp_[0]; (BV)[1] = bp_[9];                                 \
        (BV)[2] = bp_[18]; (BV)[3] = bp_[27];                               \
    } while (0)

    LOADA(0, a0A, a1A, bvA);

    // One tap: prefetch next A/bias -> 16 ds_read_b32 patches (2-way free,
    // immediate offsets) || 8 MFMA (bias as acc-init) -> ReLU+mask+FMA.
#define BODY(KK, A0C, A1C, BVC, A0N, A1N, BVN, PREF) do {                   \
        if (PREF) LOADA((KK) + 1, A0N, A1N, BVN);                           \
        const int di_ = (KK) < 3 ? 0 : ((KK) < 6 ? 1 : 2);                  \
        const int dj_ = (KK) - 3 * di_;                                     \
        const int hh_ = h + di_ - 1;                                        \
        const bool rbad_ = (hh_ < 0) || (hh_ > 127);                        \
        const int base_ = (di_ * 64 + c0 + 4 * quad) * 68 + l16 + dj_;      \
        float pv_[4][4];                                                    \
        _Pragma("unroll")                                                   \
        for (int nt_ = 0; nt_ < 4; ++nt_)                                   \
            _Pragma("unroll")                                               \
            for (int rg_ = 0; rg_ < 4; ++rg_)                               \
                pv_[nt_][rg_] = Sf[base_ + rg_ * 68 + nt_ * 16];            \
        floatx4 z_[4];                                                      \
        _Pragma("unroll")                                                   \
        for (int nt_ = 0; nt_ < 4; ++nt_) {                                 \
            floatx4 t_ = (BVC);   /* bias pre-ReLU as accumulator init */   \
            t_ = __builtin_amdgcn_mfma_f32_16x16x32_bf16((A0C), bfrag[nt_][0], t_, 0, 0, 0); \
            t_ = __builtin_amdgcn_mfma_f32_16x16x32_bf16((A1C), bfrag[nt_][1], t_, 0, 0, 0); \
            z_[nt_] = t_;                                                   \
        }                                                                   \
        const bool kA_ = (dj_ == 0) && fc;                                  \
        const bool kC_ = (dj_ == 2) && lc;                                  \
        _Pragma("unroll")                                                   \
        for (int nt_ = 0; nt_ < 4; ++nt_) {                                 \
            _Pragma("unroll")                                               \
            for (int rg_ = 0; rg_ < 4; ++rg_) {                             \
                float fv_ = fmaxf(z_[nt_][rg_], 0.f);                       \
                const bool kill_ = rbad_ || (nt_ == 0 && kA_) || (nt_ == 3 && kC_); \
                float pvv_ = kill_ ? 0.f : pv_[nt_][rg_];                   \
                acc[nt_][rg_] = fmaf(fv_, pvv_, acc[nt_][rg_]);             \
            }                                                               \
        }                                                                   \
    } while (0)

    // Rolled x2 (A/bias double-buffer), tail tap 8. Keep rolled: small code.
#pragma unroll 1
    for (int kk = 0; kk < 8; kk += 2) {
        BODY(kk,     a0A, a1A, bvA, a0B, a1B, bvB, true);
        BODY(kk + 1, a0B, a1B, bvB, a0A, a1A, bvA, true);
    }
    BODY(8, a0A, a1A, bvA, a0B, a1B, bvB, false);

#undef BODY
#undef LOADA

    // ---- epilogue: stores directly from MFMA-layout acc ----
    float* ob = out + (size_t)b * CC * HW + h * WW + w0;
#pragma unroll
    for (int nt = 0; nt < 4; ++nt)
#pragma unroll
        for (int rg = 0; rg < 4; ++rg)
            ob[(c0 + 4 * quad + rg) * HW + nt * 16 + l16] = acc[nt][rg];
}

extern "C" void kernel_launch(void* const* d_in, const int* in_sizes, int n_in,
                              void* d_out, int out_size, void* d_ws, size_t ws_size,
                              hipStream_t stream) {
    const float* x  = (const float*)d_in[0];
    const float* Wg = (const float*)d_in[1];
    const float* bg = (const float*)d_in[2];
    float* out = (float*)d_out;
    unsigned short* Wb = (unsigned short*)d_ws;   // 576*64*2 = 73728 B

    ACDA_wconv_kernel<<<dim3((OO * CC + 255) / 256), dim3(256), 0, stream>>>(Wg, Wb);
    ACDA_main_kernel<<<dim3(8 * 128 * 2), dim3(256), 0, stream>>>(x, Wb, bg, out);
}

// Round 9
// 110.683 us; speedup vs baseline: 1.0524x; 1.0249x over previous
//
#include <hip/hip_runtime.h>
#include <hip/hip_bf16.h>

#define CC 64
#define HH 128
#define WW 128
#define OO 576   // C * K * K
#define HW (HH * WW)

typedef __attribute__((ext_vector_type(8))) short short8;
typedef __attribute__((ext_vector_type(4))) float floatx4;

__device__ __forceinline__ unsigned short f2bf(float f) {
    unsigned u = __float_as_uint(f);
    u = (u + 0x7FFFu + ((u >> 16) & 1u)) >> 16;   // RTNE
    return (unsigned short)u;
}

// Pre-pass: (1) W_gen (576x64 fp32) -> bf16, PERMUTED tap-major (row o' =
// kk*64 + c  <-  src row o = c*9 + kk); (2) bias permuted tap-major f32:
// Bp[kk*64 + c] = bg[c*9 + kk]  (main kernel then loads bias as ONE b128).
__global__ void ACDA_wconv_kernel(const float* __restrict__ Wg,
                                  const float* __restrict__ bg,
                                  unsigned short* __restrict__ Wb,
                                  float* __restrict__ Bp) {
    int i = blockIdx.x * 256 + threadIdx.x;
    if (i < OO * CC) {
        int o2  = i >> 6;          // dest row
        int col = i & 63;
        int kk  = o2 >> 6;         // 0..8
        int c   = o2 & 63;
        Wb[i] = f2bf(Wg[(c * 9 + kk) * CC + col]);
    }
    if (i < OO) {                  // 576 permuted biases
        Bp[i] = bg[(i & 63) * 9 + (i >> 6)];
    }
}

// R8 post-mortem: LDS slab was right (47->43us, VALUBusy 29->41) but the
// layout was wrong: bfrag reads were 4-way bank conflicts (stride 544 = 0
// mod 32; SQ_LDS_BANK_CONFLICT 1.12M) and patches were 144 scalar b32/wave
// -> DS pipe ~20us busy (half of runtime). This round: CHANNEL-INNER slab
// S[di][s][c] (c padded to 68) makes every hot access an aligned b128 at
// structurally-minimal bank usage: patches 36 b128 (was 144 b32), bfrag 16
// b128 (was 64 b32 @4-way), staging 12 b128 writes. OOB rows/halo cols are
// ZERO-FILLED at stage time -> all kill masks deleted from the hot loop.
// DS ops/wave 258 -> ~66.
__global__ __launch_bounds__(256, 4) void ACDA_main_kernel(
    const float* __restrict__ x, const unsigned short* __restrict__ Wb,
    const float* __restrict__ Bp, float* __restrict__ out)
{
    // S[di][s][c]: di = tap row (h-1,h,h+1; zeroed if OOB), s = col slot
    // (0 = left halo w0-1, 1..64 = w0..w0+63, 65 = right halo w0+64; halos
    // zeroed at image edge), c = channel 0..63 (padded to 68 for b128
    // alignment & bank spread: stride 68 % 32 = 4).
    __shared__ float S[3][66][68];   // 53856 B -> 3 blocks/CU
    float* Sf = &S[0][0][0];

    const int tid  = threadIdx.x;
    const int lane = tid & 63;
    const int wv   = tid >> 6;       // 16-channel group (wave-uniform)
    const int quad = lane >> 4;
    const int l16  = lane & 15;
    const int c0   = wv * 16;

    // Bijective XCD swizzle (proven: FETCH 85->17 MB).
    const int bid = blockIdx.x;
    const int wk  = (bid & 7) * 256 + (bid >> 3);
    const int seg = wk & 1;
    const int h   = (wk >> 1) & 127;
    const int b   = wk >> 8;
    const int w0  = seg << 6;

    const float* xb = x + (size_t)b * CC * HW;

    // ---- cooperative slab staging (channel-inner, zero-filled OOB) ----
    // Thread (wv,lane): col w0+lane, channels wv*16+4i (i=0..3), rows di=0..2.
    // Global: 4 coalesced row-streams; LDS: one aligned b128 per (di,i).
#pragma unroll
    for (int di = 0; di < 3; ++di) {
        const int hh = h + di - 1;
        const bool oob = (hh < 0) || (hh > 127);     // block-uniform branch
        const int hc = hh < 0 ? 0 : (hh > 127 ? 127 : hh);
        const float* src = xb + hc * WW + w0 + lane;
#pragma unroll
        for (int i2 = 0; i2 < 4; ++i2) {
            const int c = c0 + 4 * i2;
            floatx4 v;
            if (!oob) {
                v[0] = src[(c + 0) * HW]; v[1] = src[(c + 1) * HW];
                v[2] = src[(c + 2) * HW]; v[3] = src[(c + 3) * HW];
            } else {
                v = floatx4{0.f, 0.f, 0.f, 0.f};
            }
            *(floatx4*)&Sf[(di * 66 + lane + 1) * 68 + c] = v;
        }
    }
    if (tid < 192) {   // halo cols (zero at image edge)
        const int di = tid >> 6, c = tid & 63;
        const int hh = h + di - 1;
        const bool oobR = (hh < 0) || (hh > 127);
        const int hc = hh < 0 ? 0 : (hh > 127 ? 127 : hh);
        float vL = 0.f, vR = 0.f;
        if (!oobR) {
            if (w0 > 0)        vL = xb[c * HW + hc * WW + w0 - 1];
            if (w0 + 64 < WW)  vR = xb[c * HW + hc * WW + w0 + 64];
        }
        Sf[(di * 66 + 0)  * 68 + c] = vL;
        Sf[(di * 66 + 65) * 68 + c] = vR;
    }
    __syncthreads();   // the ONLY barrier; S read-only afterwards

    // ---- B fragments from slab row di=1: two b128 per (nt,ks), pack ----
    short8 bfrag[4][2];
#pragma unroll
    for (int nt = 0; nt < 4; ++nt)
#pragma unroll
        for (int ks = 0; ks < 2; ++ks) {
            const float* p = &Sf[(66 + nt * 16 + l16 + 1) * 68 + ks * 32 + quad * 8];
            floatx4 f0 = *(const floatx4*)p;
            floatx4 f1 = *(const floatx4*)(p + 4);
            short8 v;
            __hip_bfloat162 p0 = __float22bfloat162_rn(make_float2(f0[0], f0[1]));
            __hip_bfloat162 p1 = __float22bfloat162_rn(make_float2(f0[2], f0[3]));
            __hip_bfloat162 p2 = __float22bfloat162_rn(make_float2(f1[0], f1[1]));
            __hip_bfloat162 p3 = __float22bfloat162_rn(make_float2(f1[2], f1[3]));
            unsigned u0, u1, u2, u3;
            __builtin_memcpy(&u0, &p0, 4); __builtin_memcpy(&u1, &p1, 4);
            __builtin_memcpy(&u2, &p2, 4); __builtin_memcpy(&u3, &p3, 4);
            v[0] = (short)(u0 & 0xffffu); v[1] = (short)(u0 >> 16);
            v[2] = (short)(u1 & 0xffffu); v[3] = (short)(u1 >> 16);
            v[4] = (short)(u2 & 0xffffu); v[5] = (short)(u2 >> 16);
            v[6] = (short)(u3 & 0xffffu); v[7] = (short)(u3 >> 16);
            bfrag[nt][ks] = v;
        }

    // Output accumulator in MFMA layout: acc[nt][rg] <-> channel
    // c0+4*quad+rg, pixel w0+16*nt+l16. No transpose, no masks.
    floatx4 acc[4];
#pragma unroll
    for (int nt = 0; nt < 4; ++nt) acc[nt] = floatx4{0.f, 0.f, 0.f, 0.f};

    // ---- 9 taps, fully unrolled (~3.5KB code). Per tap: A 2xb128 + bias
    // b128 (global, L2-hot) ; 4x ds_read_b128 patches ; 8 MFMA ; 16 FMA.
#pragma unroll
    for (int t = 0; t < 9; ++t) {
        const int di = t / 3;
        const int dj = t - 3 * di;
        const unsigned short* wrow = Wb + (t * 64 + c0 + l16) * CC + quad * 8;
        short8 a0 = *(const short8*)(wrow);
        short8 a1 = *(const short8*)(wrow + 32);
        floatx4 bv = *(const floatx4*)(Bp + t * 64 + c0 + 4 * quad);
        floatx4 pv[4];
#pragma unroll
        for (int nt = 0; nt < 4; ++nt)
            pv[nt] = *(const floatx4*)&Sf[(di * 66 + nt * 16 + l16 + dj) * 68 + c0 + 4 * quad];
#pragma unroll
        for (int nt = 0; nt < 4; ++nt) {
            floatx4 z = bv;   // bias pre-ReLU as accumulator init
            z = __builtin_amdgcn_mfma_f32_16x16x32_bf16(a0, bfrag[nt][0], z, 0, 0, 0);
            z = __builtin_amdgcn_mfma_f32_16x16x32_bf16(a1, bfrag[nt][1], z, 0, 0, 0);
#pragma unroll
            for (int rg = 0; rg < 4; ++rg)
                acc[nt][rg] = fmaf(fmaxf(z[rg], 0.f), pv[nt][rg], acc[nt][rg]);
        }
    }

    // ---- epilogue: stores directly from MFMA-layout acc ----
    float* ob = out + (size_t)b * CC * HW + h * WW + w0;
#pragma unroll
    for (int nt = 0; nt < 4; ++nt)
#pragma unroll
        for (int rg = 0; rg < 4; ++rg)
            ob[(c0 + 4 * quad + rg) * HW + nt * 16 + l16] = acc[nt][rg];
}

extern "C" void kernel_launch(void* const* d_in, const int* in_sizes, int n_in,
                              void* d_out, int out_size, void* d_ws, size_t ws_size,
                              hipStream_t stream) {
    const float* x  = (const float*)d_in[0];
    const float* Wg = (const float*)d_in[1];
    const float* bg = (const float*)d_in[2];
    float* out = (float*)d_out;
    unsigned short* Wb = (unsigned short*)d_ws;            // 73728 B
    float* Bp = (float*)((char*)d_ws + OO * CC * 2);       // + 2304 B = 76032 B total

    ACDA_wconv_kernel<<<dim3((OO * CC + 255) / 256), dim3(256), 0, stream>>>(Wg, bg, Wb, Bp);
    ACDA_main_kernel<<<dim3(8 * 128 * 2), dim3(256), 0, stream>>>(x, Wb, Bp, out);
}